// Round 9
// baseline (1109.331 us; speedup 1.0000x reference)
//
#include <hip/hip_runtime.h>
#include <hip/hip_cooperative_groups.h>
#include <stdint.h>

namespace cg = cooperative_groups;

#define NN 40000            // N_NODES
#define E_IN 2560000        // input edges
#define E2 5120000          // 2*E_IN, padded output size
#define NFINE 2500          // fine buckets: r>>4 (16 rows each)
#define NSB 20              // superbuckets: r>>11 (2048 rows each; sb19 partial)
#define SB_SHIFT 11
#define FINES_PER_SB 128
#define P2_TILES 66
#define SBCAP (P2_TILES*2048)  // 135168: mean 131072 + ~11 sigma (sigma~360)
#define CAPB 1280           // fine region: mean 1024 + 8 sigma (sigma~32)
#define CAPROW 256          // per-row safety clamp
#define GRID 1024           // 4 blocks/CU x 256 CU: power-of-2 waves/SIMD -> co-residable

typedef unsigned long long ull;

// ---------------- wave-level u32-key bitonic + dedupe for one row ----------------
template<int L>
__device__ __forceinline__ int sort_row(ull* dRow, int nr, int lane) {
    const int m = 64 * L;
    unsigned key[L];
#pragma unroll
    for (int s = 0; s < L; s++) {
        int v = s * 64 + lane;
        key[s] = (v < nr) ? ((((unsigned)(dRow[v] >> 32) & 0xFFFFu) << 8) | (unsigned)v)
                          : 0xFFFFFFFFu;
    }
    for (int k = 2; k <= m; k <<= 1) {
        for (int j = k >> 1; j > 0; j >>= 1) {
            if (j >= 64) {
                int js = j >> 6;
#pragma unroll
                for (int s = 0; s < L; s++) {
                    int s2 = s ^ js;
                    if (s2 > s) {
                        bool up = (((s * 64) & k) == 0);
                        unsigned a = key[s], b = key[s2];
                        bool sw = up ? (a > b) : (a < b);
                        key[s]  = sw ? b : a;
                        key[s2] = sw ? a : b;
                    }
                }
            } else {
#pragma unroll
                for (int s = 0; s < L; s++) {
                    unsigned partner = __shfl_xor(key[s], j, 64);
                    int v = s * 64 + lane;
                    bool up = ((v & k) == 0);
                    bool lower = ((lane & j) == 0);
                    bool keepmin = (lower == up);
                    unsigned mn = key[s] < partner ? key[s] : partner;
                    unsigned mx = key[s] < partner ? partner : key[s];
                    key[s] = keepmin ? mn : mx;
                }
            }
        }
    }
    ull lmask = (1ull << lane) - 1;
    bool head[L];
    int rank[L];
    int base = 0;
#pragma unroll
    for (int s = 0; s < L; s++) {
        unsigned pv = __shfl_up(key[s], 1, 64);
        unsigned tl = (s > 0) ? __shfl(key[s - 1], 63, 64) : 0u;
        unsigned prev = (lane == 0) ? tl : pv;
        int v = s * 64 + lane;
        head[s] = (key[s] != 0xFFFFFFFFu) && (v == 0 || (key[s] >> 8) != (prev >> 8));
        ull msk = __ballot(head[s]);
        rank[s] = base + __popcll(msk & lmask);
        base += __popcll(msk);
    }
    int total = base;
    ull full[L];
#pragma unroll
    for (int s = 0; s < L; s++)
        full[s] = (key[s] != 0xFFFFFFFFu) ? dRow[key[s] & 255u] : 0ull;
    __builtin_amdgcn_wave_barrier();
#pragma unroll
    for (int s = 0; s < L; s++) {
        int v = s * 64 + lane;
        if (v < nr) dRow[v] = full[s];
    }
    __builtin_amdgcn_wave_barrier();
    float acc[L];
#pragma unroll
    for (int s = 0; s < L; s++) {
        if (head[s]) {
            float a = __uint_as_float((unsigned)(full[s] & 0xFFFFFFFFu));
            int v = s * 64 + lane;
            for (int q = v + 1; q < nr; q++) {
                ull x = dRow[q];
                if ((x >> 32) != (full[s] >> 32)) break;
                a += __uint_as_float((unsigned)(x & 0xFFFFFFFFu));
            }
            acc[s] = a;
        }
    }
    __builtin_amdgcn_wave_barrier();
#pragma unroll
    for (int s = 0; s < L; s++) {
        if (head[s])
            dRow[rank[s]] = (full[s] & 0xFFFFFFFF00000000ull) | (ull)__float_as_uint(acc[s]);
    }
    return total;
}

// ======================================================================
//  FUSED cooperative kernel (primary path)
// ======================================================================
__global__ void __launch_bounds__(256, 4) k_fused(const int* __restrict__ ei,
                                                  const float* __restrict__ ea,
                                                  const float* __restrict__ t,
                                                  int* __restrict__ sbCursor,
                                                  int* __restrict__ fineCursor,
                                                  int* __restrict__ uniqueCount,
                                                  int* __restrict__ outBase,
                                                  ull* __restrict__ pairs1,
                                                  ull* __restrict__ pairs2,
                                                  float* __restrict__ out) {
    cg::grid_group gridg = cg::this_grid();
    __shared__ __align__(16) char smem[17936];
    int tid = threadIdx.x;
    int bid = blockIdx.x;

    // ======== phase 0: init cursors to fixed region bases ========
    for (int f = bid * 256 + tid; f < NFINE; f += GRID * 256) fineCursor[f] = f * CAPB;
    if (bid == 0 && tid < NSB) sbCursor[tid] = tid * SBCAP;
    __threadfence();
    gridg.sync();

    // ======== phase 1: partition entries -> 20 fixed superbucket regions ========
    {
        ull* staged = (ull*)smem;
        int* cnt    = (int*)(smem + 16384);
        int* off    = (int*)(smem + 16896);
        int* gbase  = (int*)(smem + 17424);
        float t0 = t[0];
        for (int tile = bid; tile < E_IN / 1024; tile += GRID) {
            if (tid < NSB) cnt[tid] = 0;
            __syncthreads();
            int tileStart = tile * 1024;
            ull eA[4], eB[4];
            int rkA[4], rkB[4];
            bool keep[4];
#pragma unroll
            for (int k = 0; k < 4; k++) {
                int i = tileStart + tid + k * 256;
                float a = ea[i];
                keep[k] = (a <= t0);
                if (keep[k]) {
                    int r = ei[i], c = ei[E_IN + i];
                    unsigned ab = __float_as_uint(a);
                    eA[k] = ((ull)(unsigned)r << 48) | ((ull)(unsigned)c << 32) | ab;
                    eB[k] = ((ull)(unsigned)c << 48) | ((ull)(unsigned)r << 32) | ab;
                    rkA[k] = atomicAdd(&cnt[r >> SB_SHIFT], 1);
                    rkB[k] = atomicAdd(&cnt[c >> SB_SHIFT], 1);
                }
            }
            __syncthreads();
            if (tid == 0) {
                int acc = 0;
                for (int s = 0; s < NSB; s++) { off[s] = acc; acc += cnt[s]; }
                off[NSB] = acc;
            }
            __syncthreads();
            if (tid < NSB) gbase[tid] = atomicAdd(&sbCursor[tid], cnt[tid]);
#pragma unroll
            for (int k = 0; k < 4; k++) {
                if (keep[k]) {
                    staged[off[(int)(eA[k] >> 59)] + rkA[k]] = eA[k];
                    staged[off[(int)(eB[k] >> 59)] + rkB[k]] = eB[k];
                }
            }
            __syncthreads();
            int total = off[NSB];
            for (int i = tid; i < total; i += 256) {
                ull e = staged[i];
                int sb = (int)(e >> 59);
                pairs1[gbase[sb] + (i - off[sb])] = e;
            }
            __syncthreads();
        }
    }
    __threadfence();
    gridg.sync();

    // ======== phase 2: superbucket -> 128 fixed fine regions ========
    {
        ull* staged = (ull*)smem;
        int* cnt    = (int*)(smem + 16384);
        int* off    = (int*)(smem + 16896);
        int* gbase  = (int*)(smem + 17424);
        for (int w = bid; w < NSB * P2_TILES; w += GRID) {
            int sb = w / P2_TILES;
            int tile = w % P2_TILES;
            int regionBase = sb * SBCAP;
            int len = sbCursor[sb] - regionBase;
            if (len > SBCAP) len = SBCAP;               // defensive clamp
            int start = tile * 2048;
            if (start >= len) continue;
            int cntT = len - start; if (cntT > 2048) cntT = 2048;
            const ull* src = pairs1 + regionBase + start;
            int fineFirst = sb * FINES_PER_SB;
            int nF = NFINE - fineFirst; if (nF > FINES_PER_SB) nF = FINES_PER_SB;

            if (tid < FINES_PER_SB) { cnt[tid] = 0; gbase[tid] = 0; }
            __syncthreads();
            ull e[8];
            int rk[8];
#pragma unroll
            for (int k = 0; k < 8; k++) {
                int i = tid + k * 256;
                if (i < cntT) {
                    e[k] = src[i];
                    rk[k] = atomicAdd(&cnt[(int)(e[k] >> 52) & 127], 1);
                }
            }
            __syncthreads();
            if (tid == 0) {
                int acc = 0;
                for (int s = 0; s < FINES_PER_SB; s++) { off[s] = acc; acc += cnt[s]; }
                off[FINES_PER_SB] = acc;
            }
            __syncthreads();
            if (tid < nF) gbase[tid] = atomicAdd(&fineCursor[fineFirst + tid], cnt[tid]);
#pragma unroll
            for (int k = 0; k < 8; k++) {
                int i = tid + k * 256;
                if (i < cntT) staged[off[(int)(e[k] >> 52) & 127] + rk[k]] = e[k];
            }
            __syncthreads();
            int total = off[FINES_PER_SB];
            for (int i = tid; i < total; i += 256) {
                ull v = staged[i];
                int lb = (int)(v >> 52) & 127;
                pairs2[gbase[lb] + (i - off[lb])] = v;
            }
            __syncthreads();
        }
    }
    __threadfence();
    gridg.sync();

    // ======== phase 3: row-partition in LDS + per-row wave sort + compact ========
    {
        ull* d     = (ull*)smem;
        int* rcnt  = (int*)(smem + 10240);
        int* roff  = (int*)(smem + 10304);
        int* ucnt  = (int*)(smem + 10384);
        int* ubase = (int*)(smem + 10448);
        int lane = tid & 63, wave = tid >> 6;
        for (int b = bid; b < NFINE; b += GRID) {
            int base = b * CAPB;
            int n = fineCursor[b] - base;
            if (n > CAPB) n = CAPB;
            if (tid < 16) rcnt[tid] = 0;
            __syncthreads();
            ull e[5];
            int rk[5];
#pragma unroll
            for (int k = 0; k < 5; k++) {
                int i = tid + k * 256;
                if (i < n) {
                    e[k] = pairs2[base + i];
                    rk[k] = atomicAdd(&rcnt[(int)(e[k] >> 48) & 15], 1);
                }
            }
            __syncthreads();
            if (tid == 0) {
                int acc = 0;
                for (int s = 0; s < 16; s++) { roff[s] = acc; acc += rcnt[s]; }
                roff[16] = acc;
            }
            __syncthreads();
#pragma unroll
            for (int k = 0; k < 5; k++) {
                int i = tid + k * 256;
                if (i < n) d[roff[(int)(e[k] >> 48) & 15] + rk[k]] = e[k];
            }
            __syncthreads();
            for (int rr = wave; rr < 16; rr += 4) {
                int lo = roff[rr];
                int nr = roff[rr + 1] - lo;
                if (nr > CAPROW) nr = CAPROW;
                int total;
                if (nr <= 64)       total = sort_row<1>(d + lo, nr, lane);
                else if (nr <= 128) total = sort_row<2>(d + lo, nr, lane);
                else                total = sort_row<4>(d + lo, nr, lane);
                if (lane == 0) ucnt[rr] = total;
            }
            __syncthreads();
            if (tid == 0) {
                int acc = 0;
                for (int s = 0; s < 16; s++) { ubase[s] = acc; acc += ucnt[s]; }
                uniqueCount[b] = acc;
            }
            __syncthreads();
            for (int rr = wave; rr < 16; rr += 4) {
                int u = ucnt[rr], lo = roff[rr], ub = ubase[rr];
                for (int j = lane; j < u; j += 64)
                    pairs2[base + ub + j] = d[lo + j];
            }
            __syncthreads();
        }
    }
    __threadfence();
    gridg.sync();

    // ======== phase 4: exclusive scan over uniqueCount (block 0 only) ========
    if (bid == 0) {
        int* partial = (int*)smem;
        const int PER = 10;                 // 256*10 = 2560 >= 2501
        int start = tid * PER;
        int v[PER], sum = 0;
#pragma unroll
        for (int k = 0; k < PER; k++) {
            int i = start + k;
            int x = (i < NFINE) ? uniqueCount[i] : 0;
            v[k] = sum;
            sum += x;
        }
        partial[tid] = sum;
        __syncthreads();
        for (int off = 1; off < 256; off <<= 1) {
            int add = (tid >= off) ? partial[tid - off] : 0;
            __syncthreads();
            partial[tid] += add;
            __syncthreads();
        }
        int base = partial[tid] - sum;
#pragma unroll
        for (int k = 0; k < PER; k++) {
            int i = start + k;
            if (i < NFINE) outBase[i] = base + v[k];
        }
        if (tid == 255) {
            outBase[NFINE] = partial[255];
            out[(size_t)3 * E2] = (float)partial[255];   // num_edges as f32
        }
    }
    __threadfence();
    gridg.sync();

    // ======== phase 5: fused pad-fill + write-out, x4 vectorized ========
    {
        int* sOB = (int*)smem;
        for (int i = tid; i <= NFINE; i += 256) sOB[i] = outBase[i];
        __syncthreads();
        int T = sOB[NFINE];
        for (int tile = bid; tile < E2 / 1024; tile += GRID) {
            int j0 = (tile * 256 + tid) * 4;
            float rr[4], cc[4], aa[4];
            int lo = 0;
            if (j0 < T) {
                int hi = NFINE;
                while (hi - lo > 1) {
                    int mid = (lo + hi) >> 1;
                    if (sOB[mid] <= j0) lo = mid; else hi = mid;
                }
            }
#pragma unroll
            for (int k = 0; k < 4; k++) {
                int j = j0 + k;
                if (j < T) {
                    while (lo < NFINE - 1 && sOB[lo + 1] <= j) lo++;
                    ull e = pairs2[lo * CAPB + (j - sOB[lo])];
                    rr[k] = (float)(int)(e >> 48);
                    cc[k] = (float)(int)((e >> 32) & 0xFFFF);
                    aa[k] = __uint_as_float((unsigned)(e & 0xFFFFFFFFu));
                } else { rr[k] = -1.0f; cc[k] = -1.0f; aa[k] = 0.0f; }
            }
            *(float4*)(out + j0)          = make_float4(rr[0], rr[1], rr[2], rr[3]);
            *(float4*)(out + E2 + j0)     = make_float4(cc[0], cc[1], cc[2], cc[3]);
            *(float4*)(out + 2 * E2 + j0) = make_float4(aa[0], aa[1], aa[2], aa[3]);
        }
    }
}

// ======================================================================
//  Fallback path: the proven R7 six-kernel sequence
// ======================================================================
__global__ void k_init(int* __restrict__ sbCursor, int* __restrict__ fineCursor) {
    int tid = threadIdx.x;
    for (int f = tid; f < NFINE; f += 256) fineCursor[f] = f * CAPB;
    if (tid < NSB) sbCursor[tid] = tid * SBCAP;
}

__global__ void __launch_bounds__(256) k_part1(const int* __restrict__ ei,
                                               const float* __restrict__ ea,
                                               const float* __restrict__ t,
                                               int* __restrict__ sbCursor,
                                               ull* __restrict__ pairs1) {
    __shared__ ull staged[2048];
    __shared__ int cnt[NSB], off[NSB + 1], gbase[NSB];
    int tid = threadIdx.x;
    if (tid < NSB) cnt[tid] = 0;
    __syncthreads();
    float t0 = t[0];
    int tileStart = blockIdx.x * 1024;

    ull eA[4], eB[4];
    int rkA[4], rkB[4];
    bool keep[4];
#pragma unroll
    for (int k = 0; k < 4; k++) {
        int i = tileStart + tid + k * 256;
        float a = ea[i];
        keep[k] = (a <= t0);
        if (keep[k]) {
            int r = ei[i], c = ei[E_IN + i];
            unsigned ab = __float_as_uint(a);
            eA[k] = ((ull)(unsigned)r << 48) | ((ull)(unsigned)c << 32) | ab;
            eB[k] = ((ull)(unsigned)c << 48) | ((ull)(unsigned)r << 32) | ab;
            rkA[k] = atomicAdd(&cnt[r >> SB_SHIFT], 1);
            rkB[k] = atomicAdd(&cnt[c >> SB_SHIFT], 1);
        }
    }
    __syncthreads();
    if (tid == 0) {
        int acc = 0;
        for (int s = 0; s < NSB; s++) { off[s] = acc; acc += cnt[s]; }
        off[NSB] = acc;
    }
    __syncthreads();
    if (tid < NSB) gbase[tid] = atomicAdd(&sbCursor[tid], cnt[tid]);
#pragma unroll
    for (int k = 0; k < 4; k++) {
        if (keep[k]) {
            staged[off[(int)(eA[k] >> 59)] + rkA[k]] = eA[k];
            staged[off[(int)(eB[k] >> 59)] + rkB[k]] = eB[k];
        }
    }
    __syncthreads();
    int total = off[NSB];
    for (int i = tid; i < total; i += 256) {
        ull e = staged[i];
        int sb = (int)(e >> 59);
        pairs1[gbase[sb] + (i - off[sb])] = e;
    }
}

__global__ void __launch_bounds__(256) k_part2(const int* __restrict__ sbCursor,
                                               int* __restrict__ fineCursor,
                                               const ull* __restrict__ pairs1,
                                               ull* __restrict__ pairs2) {
    int sb = blockIdx.x / P2_TILES;
    int tile = blockIdx.x % P2_TILES;
    int regionBase = sb * SBCAP;
    int len = sbCursor[sb] - regionBase;
    if (len > SBCAP) len = SBCAP;
    int start = tile * 2048;
    if (start >= len) return;
    int cntT = len - start; if (cntT > 2048) cntT = 2048;
    const ull* src = pairs1 + regionBase + start;

    int fineFirst = sb * FINES_PER_SB;
    int nF = NFINE - fineFirst; if (nF > FINES_PER_SB) nF = FINES_PER_SB;

    __shared__ ull staged[2048];
    __shared__ int cnt[FINES_PER_SB], off[FINES_PER_SB + 1], gbase[FINES_PER_SB];
    int tid = threadIdx.x;
    if (tid < FINES_PER_SB) { cnt[tid] = 0; gbase[tid] = 0; }
    __syncthreads();

    ull e[8];
    int rk[8];
#pragma unroll
    for (int k = 0; k < 8; k++) {
        int i = tid + k * 256;
        if (i < cntT) {
            e[k] = src[i];
            rk[k] = atomicAdd(&cnt[(int)(e[k] >> 52) & 127], 1);
        }
    }
    __syncthreads();
    if (tid == 0) {
        int acc = 0;
        for (int s = 0; s < FINES_PER_SB; s++) { off[s] = acc; acc += cnt[s]; }
        off[FINES_PER_SB] = acc;
    }
    __syncthreads();
    if (tid < nF) gbase[tid] = atomicAdd(&fineCursor[fineFirst + tid], cnt[tid]);
#pragma unroll
    for (int k = 0; k < 8; k++) {
        int i = tid + k * 256;
        if (i < cntT) staged[off[(int)(e[k] >> 52) & 127] + rk[k]] = e[k];
    }
    __syncthreads();
    int total = off[FINES_PER_SB];
    for (int i = tid; i < total; i += 256) {
        ull v = staged[i];
        int lb = (int)(v >> 52) & 127;
        pairs2[gbase[lb] + (i - off[lb])] = v;
    }
}

__global__ void __launch_bounds__(256) k_sortrows(const int* __restrict__ fineCursor,
                                                  ull* __restrict__ pairs2,
                                                  int* __restrict__ uniqueCount) {
    int b = blockIdx.x;
    int base = b * CAPB;
    int n = fineCursor[b] - base;
    if (n > CAPB) n = CAPB;
    __shared__ ull d[CAPB];
    __shared__ int rcnt[16], roff[17], ucnt[16], ubase[16];
    int tid = threadIdx.x;
    if (tid < 16) rcnt[tid] = 0;
    __syncthreads();
    ull e[5];
    int rk[5];
#pragma unroll
    for (int k = 0; k < 5; k++) {
        int i = tid + k * 256;
        if (i < n) {
            e[k] = pairs2[base + i];
            rk[k] = atomicAdd(&rcnt[(int)(e[k] >> 48) & 15], 1);
        }
    }
    __syncthreads();
    if (tid == 0) {
        int acc = 0;
        for (int s = 0; s < 16; s++) { roff[s] = acc; acc += rcnt[s]; }
        roff[16] = acc;
    }
    __syncthreads();
#pragma unroll
    for (int k = 0; k < 5; k++) {
        int i = tid + k * 256;
        if (i < n) d[roff[(int)(e[k] >> 48) & 15] + rk[k]] = e[k];
    }
    __syncthreads();
    int lane = tid & 63, wave = tid >> 6;
    for (int rr = wave; rr < 16; rr += 4) {
        int lo = roff[rr];
        int nr = roff[rr + 1] - lo;
        if (nr > CAPROW) nr = CAPROW;
        int total;
        if (nr <= 64)       total = sort_row<1>(d + lo, nr, lane);
        else if (nr <= 128) total = sort_row<2>(d + lo, nr, lane);
        else                total = sort_row<4>(d + lo, nr, lane);
        if (lane == 0) ucnt[rr] = total;
    }
    __syncthreads();
    if (tid == 0) {
        int acc = 0;
        for (int s = 0; s < 16; s++) { ubase[s] = acc; acc += ucnt[s]; }
        uniqueCount[b] = acc;
    }
    __syncthreads();
    for (int rr = wave; rr < 16; rr += 4) {
        int u = ucnt[rr], lo = roff[rr], ub = ubase[rr];
        for (int j = lane; j < u; j += 64)
            pairs2[base + ub + j] = d[lo + j];
    }
}

__global__ void __launch_bounds__(1024) k_scan(const int* __restrict__ in, int n,
                                               int* __restrict__ outExcl,
                                               float* __restrict__ totalDst) {
    __shared__ int partial[1024];
    int tid = threadIdx.x;
    int start = tid * 3;
    int v[3], sum = 0;
#pragma unroll
    for (int k = 0; k < 3; k++) {
        int i = start + k;
        int x = (i < n) ? in[i] : 0;
        v[k] = sum;
        sum += x;
    }
    partial[tid] = sum;
    __syncthreads();
    for (int off = 1; off < 1024; off <<= 1) {
        int add = (tid >= off) ? partial[tid - off] : 0;
        __syncthreads();
        partial[tid] += add;
        __syncthreads();
    }
    int base = partial[tid] - sum;
#pragma unroll
    for (int k = 0; k < 3; k++) {
        int i = start + k;
        if (i < n) outExcl[i] = base + v[k];
    }
    if (tid == 1023) {
        outExcl[n] = partial[1023];
        if (totalDst) totalDst[0] = (float)partial[1023];
    }
}

__global__ void __launch_bounds__(256) k_outfill(const int* __restrict__ outBase,
                                                 const ull* __restrict__ pairs2,
                                                 float* __restrict__ out) {
    __shared__ int sOB[NFINE + 1];
    int tid = threadIdx.x;
    for (int i = tid; i <= NFINE; i += 256) sOB[i] = outBase[i];
    __syncthreads();
    int j0 = (blockIdx.x * 256 + tid) * 4;
    int T = sOB[NFINE];
    float rr[4], cc[4], aa[4];
    int lo = 0;
    if (j0 < T) {
        int hi = NFINE;
        while (hi - lo > 1) {
            int mid = (lo + hi) >> 1;
            if (sOB[mid] <= j0) lo = mid; else hi = mid;
        }
    }
#pragma unroll
    for (int k = 0; k < 4; k++) {
        int j = j0 + k;
        if (j < T) {
            while (lo < NFINE - 1 && sOB[lo + 1] <= j) lo++;
            ull e = pairs2[lo * CAPB + (j - sOB[lo])];
            rr[k] = (float)(int)(e >> 48);
            cc[k] = (float)(int)((e >> 32) & 0xFFFF);
            aa[k] = __uint_as_float((unsigned)(e & 0xFFFFFFFFu));
        } else { rr[k] = -1.0f; cc[k] = -1.0f; aa[k] = 0.0f; }
    }
    *(float4*)(out + j0)          = make_float4(rr[0], rr[1], rr[2], rr[3]);
    *(float4*)(out + E2 + j0)     = make_float4(cc[0], cc[1], cc[2], cc[3]);
    *(float4*)(out + 2 * E2 + j0) = make_float4(aa[0], aa[1], aa[2], aa[3]);
}

extern "C" void kernel_launch(void* const* d_in, const int* in_sizes, int n_in,
                              void* d_out, int out_size, void* d_ws, size_t ws_size,
                              hipStream_t stream) {
    const int*   ei = (const int*)d_in[0];     // [2,E]: rows then cols
    const float* ea = (const float*)d_in[1];   // [E]
    const float* t  = (const float*)d_in[2];   // [1]
    float* out = (float*)d_out;                // 2*E2 indices + E2 attrs + 1 count

    int* sbCursor    = (int*)d_ws;                    // 32
    int* fineCursor  = sbCursor + 32;                 // 2500
    int* uniqueCount = fineCursor + NFINE;            // 2500
    int* outBase     = uniqueCount + NFINE;           // 2501
    ull* pairs2 = (ull*)(((uintptr_t)(outBase + NFINE + 1) + 15) & ~(uintptr_t)15);  // 2500*CAPB

    // pairs1 lives in d_out (20*SBCAP*8 = 21.6 MB < 61.4 MB): dead before out writes
    ull* pairs1 = (ull*)d_out;

    void* args[] = { (void*)&ei, (void*)&ea, (void*)&t,
                     (void*)&sbCursor, (void*)&fineCursor, (void*)&uniqueCount,
                     (void*)&outBase, (void*)&pairs1, (void*)&pairs2, (void*)&out };
    hipError_t err = hipLaunchCooperativeKernel((void*)k_fused, dim3(GRID), dim3(256),
                                                args, 0, stream);
    if (err != hipSuccess) {
        (void)hipGetLastError();   // clear sticky error; take the proven 6-kernel path
        k_init<<<1, 256, 0, stream>>>(sbCursor, fineCursor);
        k_part1<<<E_IN / 1024, 256, 0, stream>>>(ei, ea, t, sbCursor, pairs1);
        k_part2<<<NSB * P2_TILES, 256, 0, stream>>>(sbCursor, fineCursor, pairs1, pairs2);
        k_sortrows<<<NFINE, 256, 0, stream>>>(fineCursor, pairs2, uniqueCount);
        k_scan<<<1, 1024, 0, stream>>>(uniqueCount, NFINE, outBase, out + (size_t)3 * E2);
        k_outfill<<<E2 / 1024, 256, 0, stream>>>(outBase, pairs2, out);
    }
}

// Round 10
// 260.212 us; speedup vs baseline: 4.2632x; 4.2632x over previous
//
#include <hip/hip_runtime.h>
#include <stdint.h>

#define NN 40000            // N_NODES
#define E_IN 2560000        // input edges
#define E2 5120000          // 2*E_IN, padded output size
#define NFINE 2500          // fine buckets: r>>4 (16 rows each)
#define NSB 20              // superbuckets: r>>11 (2048 rows each; sb19 partial)
#define SB_SHIFT 11
#define FINES_PER_SB 128
#define P2_TILES 66
#define SBCAP (P2_TILES*2048)  // 135168: mean 131072 + ~11 sigma (sigma~360)
#define CAPB 1280           // fine region: mean 1024 + 8 sigma (sigma~32)
#define CAPROW 256          // per-row safety clamp

typedef unsigned long long ull;

// ---------------- wave-level u32-key bitonic + dedupe for one row ----------------
// Entries in a row share r; sort key = (c<<8)|slot (u32, 1 shfl/stage), gather
// full u64 entries by slot afterward. Compacted result at dRow[0..total).
template<int L>
__device__ __forceinline__ int sort_row(ull* dRow, int nr, int lane) {
    const int m = 64 * L;
    unsigned key[L];
#pragma unroll
    for (int s = 0; s < L; s++) {
        int v = s * 64 + lane;
        key[s] = (v < nr) ? ((((unsigned)(dRow[v] >> 32) & 0xFFFFu) << 8) | (unsigned)v)
                          : 0xFFFFFFFFu;
    }
    for (int k = 2; k <= m; k <<= 1) {
        for (int j = k >> 1; j > 0; j >>= 1) {
            if (j >= 64) {
                int js = j >> 6;
#pragma unroll
                for (int s = 0; s < L; s++) {
                    int s2 = s ^ js;
                    if (s2 > s) {
                        bool up = (((s * 64) & k) == 0);   // k>=128: lane bits irrelevant
                        unsigned a = key[s], b = key[s2];
                        bool sw = up ? (a > b) : (a < b);
                        key[s]  = sw ? b : a;
                        key[s2] = sw ? a : b;
                    }
                }
            } else {
#pragma unroll
                for (int s = 0; s < L; s++) {
                    unsigned partner = __shfl_xor(key[s], j, 64);
                    int v = s * 64 + lane;
                    bool up = ((v & k) == 0);
                    bool lower = ((lane & j) == 0);
                    bool keepmin = (lower == up);
                    unsigned mn = key[s] < partner ? key[s] : partner;
                    unsigned mx = key[s] < partner ? partner : key[s];
                    key[s] = keepmin ? mn : mx;
                }
            }
        }
    }
    ull lmask = (1ull << lane) - 1;
    bool head[L];
    int rank[L];
    int base = 0;
#pragma unroll
    for (int s = 0; s < L; s++) {
        unsigned pv = __shfl_up(key[s], 1, 64);
        unsigned tl = (s > 0) ? __shfl(key[s - 1], 63, 64) : 0u;
        unsigned prev = (lane == 0) ? tl : pv;
        int v = s * 64 + lane;
        head[s] = (key[s] != 0xFFFFFFFFu) && (v == 0 || (key[s] >> 8) != (prev >> 8));
        ull msk = __ballot(head[s]);
        rank[s] = base + __popcll(msk & lmask);
        base += __popcll(msk);
    }
    int total = base;
    ull full[L];
#pragma unroll
    for (int s = 0; s < L; s++)
        full[s] = (key[s] != 0xFFFFFFFFu) ? dRow[key[s] & 255u] : 0ull;
    __builtin_amdgcn_wave_barrier();     // gathers before overwrite (DS in-order per wave)
#pragma unroll
    for (int s = 0; s < L; s++) {
        int v = s * 64 + lane;
        if (v < nr) dRow[v] = full[s];
    }
    __builtin_amdgcn_wave_barrier();
    float acc[L];
#pragma unroll
    for (int s = 0; s < L; s++) {
        if (head[s]) {
            float a = __uint_as_float((unsigned)(full[s] & 0xFFFFFFFFu));
            int v = s * 64 + lane;
            for (int q = v + 1; q < nr; q++) {
                ull x = dRow[q];
                if ((x >> 32) != (full[s] >> 32)) break;
                a += __uint_as_float((unsigned)(x & 0xFFFFFFFFu));
            }
            acc[s] = a;
        }
    }
    __builtin_amdgcn_wave_barrier();     // run reads before compacted writes
#pragma unroll
    for (int s = 0; s < L; s++) {
        if (head[s])
            dRow[rank[s]] = (full[s] & 0xFFFFFFFF00000000ull) | (ull)__float_as_uint(acc[s]);
    }
    return total;
}

// ---------------- K1: partition pass 1 + embedded fineCursor init ----------------
// sbCursor is RELATIVE (memset to 0 on host side); region base added here.
// grid == 2500 == NFINE, so each block also inits one fineCursor slot (read
// only by k_part2, after the kernel boundary).
__global__ void __launch_bounds__(256) k_part1(const int* __restrict__ ei,
                                               const float* __restrict__ ea,
                                               const float* __restrict__ t,
                                               int* __restrict__ sbCursor,
                                               int* __restrict__ fineCursor,
                                               ull* __restrict__ pairs1) {
    if (threadIdx.x == 0) fineCursor[blockIdx.x] = blockIdx.x * CAPB;

    __shared__ ull staged[2048];
    __shared__ int cnt[NSB], off[NSB + 1], gbase[NSB];
    int tid = threadIdx.x;
    if (tid < NSB) cnt[tid] = 0;
    __syncthreads();
    float t0 = t[0];
    int tileStart = blockIdx.x * 1024;          // 2500*1024 == E_IN exactly

    ull eA[4], eB[4];
    int rkA[4], rkB[4];
    bool keep[4];
#pragma unroll
    for (int k = 0; k < 4; k++) {
        int i = tileStart + tid + k * 256;
        float a = ea[i];
        keep[k] = (a <= t0);
        if (keep[k]) {
            int r = ei[i], c = ei[E_IN + i];
            unsigned ab = __float_as_uint(a);
            eA[k] = ((ull)(unsigned)r << 48) | ((ull)(unsigned)c << 32) | ab;
            eB[k] = ((ull)(unsigned)c << 48) | ((ull)(unsigned)r << 32) | ab;
            rkA[k] = atomicAdd(&cnt[r >> SB_SHIFT], 1);
            rkB[k] = atomicAdd(&cnt[c >> SB_SHIFT], 1);
        }
    }
    __syncthreads();
    if (tid == 0) {
        int acc = 0;
        for (int s = 0; s < NSB; s++) { off[s] = acc; acc += cnt[s]; }
        off[NSB] = acc;
    }
    __syncthreads();
    if (tid < NSB) gbase[tid] = tid * SBCAP + atomicAdd(&sbCursor[tid], cnt[tid]);
#pragma unroll
    for (int k = 0; k < 4; k++) {
        if (keep[k]) {
            staged[off[(int)(eA[k] >> 59)] + rkA[k]] = eA[k];
            staged[off[(int)(eB[k] >> 59)] + rkB[k]] = eB[k];
        }
    }
    __syncthreads();
    int total = off[NSB];
    for (int i = tid; i < total; i += 256) {
        ull e = staged[i];
        int sb = (int)(e >> 59);
        pairs1[gbase[sb] + (i - off[sb])] = e;
    }
}

// ---------------- K2: partition pass 2 — superbucket -> 128 fixed fine regions ----------------
__global__ void __launch_bounds__(256) k_part2(const int* __restrict__ sbCursor,
                                               int* __restrict__ fineCursor,
                                               const ull* __restrict__ pairs1,
                                               ull* __restrict__ pairs2) {
    int sb = blockIdx.x / P2_TILES;
    int tile = blockIdx.x % P2_TILES;
    int len = sbCursor[sb];                     // relative cursor == count
    if (len > SBCAP) len = SBCAP;               // defensive clamp
    int start = tile * 2048;
    if (start >= len) return;
    int cntT = len - start; if (cntT > 2048) cntT = 2048;
    const ull* src = pairs1 + sb * SBCAP + start;

    int fineFirst = sb * FINES_PER_SB;
    int nF = NFINE - fineFirst; if (nF > FINES_PER_SB) nF = FINES_PER_SB;

    __shared__ ull staged[2048];
    __shared__ int cnt[FINES_PER_SB], off[FINES_PER_SB + 1], gbase[FINES_PER_SB];
    int tid = threadIdx.x;
    if (tid < FINES_PER_SB) { cnt[tid] = 0; gbase[tid] = 0; }   // gbase zero-init: defense
    __syncthreads();

    ull e[8];
    int rk[8];
#pragma unroll
    for (int k = 0; k < 8; k++) {
        int i = tid + k * 256;
        if (i < cntT) {
            e[k] = src[i];
            rk[k] = atomicAdd(&cnt[(int)(e[k] >> 52) & 127], 1);
        }
    }
    __syncthreads();
    if (tid == 0) {
        int acc = 0;
        for (int s = 0; s < FINES_PER_SB; s++) { off[s] = acc; acc += cnt[s]; }
        off[FINES_PER_SB] = acc;
    }
    __syncthreads();
    if (tid < nF) gbase[tid] = atomicAdd(&fineCursor[fineFirst + tid], cnt[tid]);
#pragma unroll
    for (int k = 0; k < 8; k++) {
        int i = tid + k * 256;
        if (i < cntT) staged[off[(int)(e[k] >> 52) & 127] + rk[k]] = e[k];
    }
    __syncthreads();
    int total = off[FINES_PER_SB];
    for (int i = tid; i < total; i += 256) {
        ull v = staged[i];
        int lb = (int)(v >> 52) & 127;
        pairs2[gbase[lb] + (i - off[lb])] = v;
    }
}

// ---------------- K3: row-partition + per-row wave sort + compact + last-block scan ----------------
__global__ void __launch_bounds__(256) k_sortrows(const int* __restrict__ fineCursor,
                                                  ull* __restrict__ pairs2,
                                                  int* __restrict__ uniqueCount,
                                                  int* __restrict__ done,
                                                  int* __restrict__ outBase,
                                                  float* __restrict__ out) {
    int b = blockIdx.x;
    int base = b * CAPB;
    int n = fineCursor[b] - base;
    if (n > CAPB) n = CAPB;
    __shared__ ull d[CAPB];
    __shared__ int rcnt[16], roff[17], ucnt[16], ubase[16];
    __shared__ int sFlag;
    __shared__ int partial[256];
    int tid = threadIdx.x;
    if (tid < 16) rcnt[tid] = 0;
    __syncthreads();
    // single global read: stage entries in regs, rank via LDS atomics
    ull e[5];
    int rk[5];
#pragma unroll
    for (int k = 0; k < 5; k++) {
        int i = tid + k * 256;
        if (i < n) {
            e[k] = pairs2[base + i];
            rk[k] = atomicAdd(&rcnt[(int)(e[k] >> 48) & 15], 1);
        }
    }
    __syncthreads();
    if (tid == 0) {
        int acc = 0;
        for (int s = 0; s < 16; s++) { roff[s] = acc; acc += rcnt[s]; }
        roff[16] = acc;
    }
    __syncthreads();
#pragma unroll
    for (int k = 0; k < 5; k++) {
        int i = tid + k * 256;
        if (i < n) d[roff[(int)(e[k] >> 48) & 15] + rk[k]] = e[k];
    }
    __syncthreads();
    // one wave per row: register bitonic + dedupe (4 waves x 4 rows)
    int lane = tid & 63, wave = tid >> 6;
    for (int rr = wave; rr < 16; rr += 4) {
        int lo = roff[rr];
        int nr = roff[rr + 1] - lo;
        if (nr > CAPROW) nr = CAPROW;      // safety clamp
        int total;
        if (nr <= 64)       total = sort_row<1>(d + lo, nr, lane);
        else if (nr <= 128) total = sort_row<2>(d + lo, nr, lane);
        else                total = sort_row<4>(d + lo, nr, lane);
        if (lane == 0) ucnt[rr] = total;
    }
    __syncthreads();
    if (tid == 0) {
        int acc = 0;
        for (int s = 0; s < 16; s++) { ubase[s] = acc; acc += ucnt[s]; }
        atomicExch(&uniqueCount[b], acc);   // device-scope publish
    }
    __syncthreads();
    // copy compacted rows back contiguous per bucket
    for (int rr = wave; rr < 16; rr += 4) {
        int u = ucnt[rr], lo = roff[rr], ub = ubase[rr];
        for (int j = lane; j < u; j += 64)
            pairs2[base + ub + j] = d[lo + j];
    }
    __syncthreads();

    // ---- last-finishing block performs the exclusive scan over uniqueCount ----
    if (tid == 0) {
        __threadfence();                    // release: publish before counting
        int prev = atomicAdd(done, 1);
        sFlag = (prev == gridDim.x - 1) ? 1 : 0;
    }
    __syncthreads();
    if (sFlag) {
        __threadfence();                    // acquire side
        const int PER = 10;                 // 256*10 = 2560 >= 2500
        int start = tid * PER;
        int v[PER], sum = 0;
#pragma unroll
        for (int k = 0; k < PER; k++) {
            int i = start + k;
            int x = (i < NFINE) ? atomicAdd(&uniqueCount[i], 0) : 0;   // device-scope load
            v[k] = sum;
            sum += x;
        }
        partial[tid] = sum;
        __syncthreads();
        for (int off = 1; off < 256; off <<= 1) {
            int add = (tid >= off) ? partial[tid - off] : 0;
            __syncthreads();
            partial[tid] += add;
            __syncthreads();
        }
        int bb = partial[tid] - sum;
#pragma unroll
        for (int k = 0; k < PER; k++) {
            int i = start + k;
            if (i < NFINE) outBase[i] = bb + v[k];
        }
        if (tid == 255) {
            outBase[NFINE] = partial[255];
            out[(size_t)3 * E2] = (float)partial[255];   // num_edges as f32
        }
    }
}

// ---------------- K4: fused pad-fill + write-out, x4 vectorized ----------------
__global__ void __launch_bounds__(256) k_outfill(const int* __restrict__ outBase,
                                                 const ull* __restrict__ pairs2,
                                                 float* __restrict__ out) {
    __shared__ int sOB[NFINE + 1];
    int tid = threadIdx.x;
    for (int i = tid; i <= NFINE; i += 256) sOB[i] = outBase[i];
    __syncthreads();
    int j0 = (blockIdx.x * 256 + tid) * 4;      // grid covers E2 exactly (5000*1024)
    int T = sOB[NFINE];
    float rr[4], cc[4], aa[4];
    int lo = 0;
    if (j0 < T) {
        int hi = NFINE;                          // invariant: sOB[lo] <= j0 < sOB[hi]
        while (hi - lo > 1) {
            int mid = (lo + hi) >> 1;
            if (sOB[mid] <= j0) lo = mid; else hi = mid;
        }
    }
#pragma unroll
    for (int k = 0; k < 4; k++) {
        int j = j0 + k;
        if (j < T) {
            while (lo < NFINE - 1 && sOB[lo + 1] <= j) lo++;   // rare bucket advance
            ull e = pairs2[lo * CAPB + (j - sOB[lo])];
            rr[k] = (float)(int)(e >> 48);
            cc[k] = (float)(int)((e >> 32) & 0xFFFF);
            aa[k] = __uint_as_float((unsigned)(e & 0xFFFFFFFFu));
        } else { rr[k] = -1.0f; cc[k] = -1.0f; aa[k] = 0.0f; }
    }
    *(float4*)(out + j0)          = make_float4(rr[0], rr[1], rr[2], rr[3]);
    *(float4*)(out + E2 + j0)     = make_float4(cc[0], cc[1], cc[2], cc[3]);
    *(float4*)(out + 2 * E2 + j0) = make_float4(aa[0], aa[1], aa[2], aa[3]);
}

extern "C" void kernel_launch(void* const* d_in, const int* in_sizes, int n_in,
                              void* d_out, int out_size, void* d_ws, size_t ws_size,
                              hipStream_t stream) {
    const int*   ei = (const int*)d_in[0];     // [2,E]: rows then cols
    const float* ea = (const float*)d_in[1];   // [E]
    const float* t  = (const float*)d_in[2];   // [1]
    float* out = (float*)d_out;                // 2*E2 indices + E2 attrs + 1 count

    // ws layout: sbCursor[32] (relative; [31] unused) | done[1] | pad | fineCursor |
    //            uniqueCount | outBase | pairs2 regions  (~25.7 MB total)
    int* sbCursor    = (int*)d_ws;                    // 32 (20 used)
    int* done        = sbCursor + 32;                 // 1
    int* fineCursor  = sbCursor + 64;                 // 2500 (init by k_part1)
    int* uniqueCount = fineCursor + NFINE;            // 2500
    int* outBase     = uniqueCount + NFINE;           // 2501
    ull* pairs2 = (ull*)(((uintptr_t)(outBase + NFINE + 1) + 15) & ~(uintptr_t)15);  // 2500*CAPB

    // pairs1 lives in d_out (20*SBCAP*8 = 21.6 MB < 61.4 MB): dead before out writes
    ull* pairs1 = (ull*)d_out;

    hipMemsetAsync(sbCursor, 0, 64 * sizeof(int), stream);   // sbCursor + done

    k_part1<<<E_IN / 1024, 256, 0, stream>>>(ei, ea, t, sbCursor, fineCursor, pairs1);
    k_part2<<<NSB * P2_TILES, 256, 0, stream>>>(sbCursor, fineCursor, pairs1, pairs2);
    k_sortrows<<<NFINE, 256, 0, stream>>>(fineCursor, pairs2, uniqueCount, done, outBase, out);
    k_outfill<<<E2 / 1024, 256, 0, stream>>>(outBase, pairs2, out);
}

// Round 11
// 211.642 us; speedup vs baseline: 5.2415x; 1.2295x over previous
//
#include <hip/hip_runtime.h>
#include <stdint.h>

#define NN 40000            // N_NODES
#define E_IN 2560000        // input edges
#define E2 5120000          // 2*E_IN, padded output size
#define NFINE 2500          // fine buckets: r>>4 (16 rows each)
#define NSB 20              // superbuckets: r>>11 (2048 rows each; sb19 partial)
#define SB_SHIFT 11
#define FINES_PER_SB 128
#define P2_TILES 66
#define SBCAP (P2_TILES*2048)  // 135168: mean 131072 + ~11 sigma (sigma~360)
#define CAPB 1280           // fine region: mean 1024 + 8 sigma (sigma~32)
#define CAPROW 256          // per-row safety clamp

typedef unsigned long long ull;

// ---------------- wave-level u32-key bitonic + dedupe for one row ----------------
// Entries in a row share r; sort key = (c<<8)|slot (u32, 1 shfl/stage), gather
// full u64 entries by slot afterward. Compacted result at dRow[0..total).
template<int L>
__device__ __forceinline__ int sort_row(ull* dRow, int nr, int lane) {
    const int m = 64 * L;
    unsigned key[L];
#pragma unroll
    for (int s = 0; s < L; s++) {
        int v = s * 64 + lane;
        key[s] = (v < nr) ? ((((unsigned)(dRow[v] >> 32) & 0xFFFFu) << 8) | (unsigned)v)
                          : 0xFFFFFFFFu;
    }
    for (int k = 2; k <= m; k <<= 1) {
        for (int j = k >> 1; j > 0; j >>= 1) {
            if (j >= 64) {
                int js = j >> 6;
#pragma unroll
                for (int s = 0; s < L; s++) {
                    int s2 = s ^ js;
                    if (s2 > s) {
                        bool up = (((s * 64) & k) == 0);   // k>=128: lane bits irrelevant
                        unsigned a = key[s], b = key[s2];
                        bool sw = up ? (a > b) : (a < b);
                        key[s]  = sw ? b : a;
                        key[s2] = sw ? a : b;
                    }
                }
            } else {
#pragma unroll
                for (int s = 0; s < L; s++) {
                    unsigned partner = __shfl_xor(key[s], j, 64);
                    int v = s * 64 + lane;
                    bool up = ((v & k) == 0);
                    bool lower = ((lane & j) == 0);
                    bool keepmin = (lower == up);
                    unsigned mn = key[s] < partner ? key[s] : partner;
                    unsigned mx = key[s] < partner ? partner : key[s];
                    key[s] = keepmin ? mn : mx;
                }
            }
        }
    }
    ull lmask = (1ull << lane) - 1;
    bool head[L];
    int rank[L];
    int base = 0;
#pragma unroll
    for (int s = 0; s < L; s++) {
        unsigned pv = __shfl_up(key[s], 1, 64);
        unsigned tl = (s > 0) ? __shfl(key[s - 1], 63, 64) : 0u;
        unsigned prev = (lane == 0) ? tl : pv;
        int v = s * 64 + lane;
        head[s] = (key[s] != 0xFFFFFFFFu) && (v == 0 || (key[s] >> 8) != (prev >> 8));
        ull msk = __ballot(head[s]);
        rank[s] = base + __popcll(msk & lmask);
        base += __popcll(msk);
    }
    int total = base;
    ull full[L];
#pragma unroll
    for (int s = 0; s < L; s++)
        full[s] = (key[s] != 0xFFFFFFFFu) ? dRow[key[s] & 255u] : 0ull;
    __builtin_amdgcn_wave_barrier();     // gathers before overwrite (DS in-order per wave)
#pragma unroll
    for (int s = 0; s < L; s++) {
        int v = s * 64 + lane;
        if (v < nr) dRow[v] = full[s];
    }
    __builtin_amdgcn_wave_barrier();
    float acc[L];
#pragma unroll
    for (int s = 0; s < L; s++) {
        if (head[s]) {
            float a = __uint_as_float((unsigned)(full[s] & 0xFFFFFFFFu));
            int v = s * 64 + lane;
            for (int q = v + 1; q < nr; q++) {
                ull x = dRow[q];
                if ((x >> 32) != (full[s] >> 32)) break;
                a += __uint_as_float((unsigned)(x & 0xFFFFFFFFu));
            }
            acc[s] = a;
        }
    }
    __builtin_amdgcn_wave_barrier();     // run reads before compacted writes
#pragma unroll
    for (int s = 0; s < L; s++) {
        if (head[s])
            dRow[rank[s]] = (full[s] & 0xFFFFFFFF00000000ull) | (ull)__float_as_uint(acc[s]);
    }
    return total;
}

// ---------------- K1: partition pass 1 (vectorized loads, per-wave counters) ----------------
// sbCursor is RELATIVE (memset 0 host-side); region base added here. grid==2500
// ==NFINE: each block also inits one fineCursor slot (read only after boundary).
__global__ void __launch_bounds__(256) k_part1(const int* __restrict__ ei,
                                               const float* __restrict__ ea,
                                               const float* __restrict__ t,
                                               int* __restrict__ sbCursor,
                                               int* __restrict__ fineCursor,
                                               ull* __restrict__ pairs1) {
    if (threadIdx.x == 0) fineCursor[blockIdx.x] = blockIdx.x * CAPB;

    __shared__ ull staged[2048];
    __shared__ int cnt[4][NSB], wb[4][NSB], off[NSB + 1], gbase[NSB];
    int tid = threadIdx.x, wave = tid >> 6;
    if (tid < 4 * NSB) ((int*)cnt)[tid] = 0;
    __syncthreads();
    float t0 = t[0];
    int i0 = blockIdx.x * 1024 + tid * 4;       // 4 consecutive edges per thread

    int4   r4 = *(const int4*)(ei + i0);
    int4   c4 = *(const int4*)(ei + E_IN + i0);
    float4 a4 = *(const float4*)(ea + i0);
    int   rr[4] = { r4.x, r4.y, r4.z, r4.w };
    int   cc[4] = { c4.x, c4.y, c4.z, c4.w };
    float aa[4] = { a4.x, a4.y, a4.z, a4.w };

    ull eA[4], eB[4];
    int rkA[4], rkB[4];
    bool keep[4];
#pragma unroll
    for (int k = 0; k < 4; k++) {
        keep[k] = (aa[k] <= t0);
        if (keep[k]) {
            unsigned ab = __float_as_uint(aa[k]);
            eA[k] = ((ull)(unsigned)rr[k] << 48) | ((ull)(unsigned)cc[k] << 32) | ab;
            eB[k] = ((ull)(unsigned)cc[k] << 48) | ((ull)(unsigned)rr[k] << 32) | ab;
            rkA[k] = atomicAdd(&cnt[wave][rr[k] >> SB_SHIFT], 1);
            rkB[k] = atomicAdd(&cnt[wave][cc[k] >> SB_SHIFT], 1);
        }
    }
    __syncthreads();
    if (tid < NSB) {
        int a0 = cnt[0][tid], a1 = cnt[1][tid], a2 = cnt[2][tid], a3 = cnt[3][tid];
        wb[0][tid] = 0; wb[1][tid] = a0; wb[2][tid] = a0 + a1; wb[3][tid] = a0 + a1 + a2;
        cnt[0][tid] = a0 + a1 + a2 + a3;        // bucket total
    }
    __syncthreads();
    if (tid == 0) {
        int acc = 0;
        for (int s = 0; s < NSB; s++) { off[s] = acc; acc += cnt[0][s]; }
        off[NSB] = acc;
    }
    __syncthreads();
    if (tid < NSB) gbase[tid] = tid * SBCAP + atomicAdd(&sbCursor[tid], cnt[0][tid]);
#pragma unroll
    for (int k = 0; k < 4; k++) {
        if (keep[k]) {
            int sA = rr[k] >> SB_SHIFT, sB = cc[k] >> SB_SHIFT;
            staged[off[sA] + wb[wave][sA] + rkA[k]] = eA[k];
            staged[off[sB] + wb[wave][sB] + rkB[k]] = eB[k];
        }
    }
    __syncthreads();
    int total = off[NSB];
    for (int i = tid; i < total; i += 256) {
        ull e = staged[i];
        int sb = (int)(e >> 59);
        pairs1[gbase[sb] + (i - off[sb])] = e;
    }
}

// ---------------- K2: partition pass 2 (per-wave counters, contiguous 64B loads) ----------------
__global__ void __launch_bounds__(256) k_part2(const int* __restrict__ sbCursor,
                                               int* __restrict__ fineCursor,
                                               const ull* __restrict__ pairs1,
                                               ull* __restrict__ pairs2) {
    int sb = blockIdx.x / P2_TILES;
    int tile = blockIdx.x % P2_TILES;
    int len = sbCursor[sb];                     // relative cursor == count
    if (len > SBCAP) len = SBCAP;               // defensive clamp
    int start = tile * 2048;
    if (start >= len) return;
    int cntT = len - start; if (cntT > 2048) cntT = 2048;
    const ull* src = pairs1 + sb * SBCAP + start;

    int fineFirst = sb * FINES_PER_SB;
    int nF = NFINE - fineFirst; if (nF > FINES_PER_SB) nF = FINES_PER_SB;

    __shared__ ull staged[2048];
    __shared__ int cnt[4][FINES_PER_SB], wb[4][FINES_PER_SB];
    __shared__ int off[FINES_PER_SB + 1], gbase[FINES_PER_SB];
    int tid = threadIdx.x, wave = tid >> 6;
    for (int i = tid; i < 4 * FINES_PER_SB; i += 256) ((int*)cnt)[i] = 0;
    if (tid < FINES_PER_SB) gbase[tid] = 0;     // defense
    __syncthreads();

    ull e[8];
    int rk[8];
    int tb = tid * 8;                           // 8 contiguous entries -> 64B/thread
#pragma unroll
    for (int k = 0; k < 8; k++) {
        int i = tb + k;
        if (i < cntT) {
            e[k] = src[i];
            rk[k] = atomicAdd(&cnt[wave][(int)(e[k] >> 52) & 127], 1);
        }
    }
    __syncthreads();
    if (tid < FINES_PER_SB) {
        int a0 = cnt[0][tid], a1 = cnt[1][tid], a2 = cnt[2][tid], a3 = cnt[3][tid];
        wb[0][tid] = 0; wb[1][tid] = a0; wb[2][tid] = a0 + a1; wb[3][tid] = a0 + a1 + a2;
        cnt[0][tid] = a0 + a1 + a2 + a3;
    }
    __syncthreads();
    if (tid == 0) {
        int acc = 0;
        for (int s = 0; s < FINES_PER_SB; s++) { off[s] = acc; acc += cnt[0][s]; }
        off[FINES_PER_SB] = acc;
    }
    __syncthreads();
    if (tid < nF) gbase[tid] = atomicAdd(&fineCursor[fineFirst + tid], cnt[0][tid]);
#pragma unroll
    for (int k = 0; k < 8; k++) {
        int i = tb + k;
        if (i < cntT) {
            int lb = (int)(e[k] >> 52) & 127;
            staged[off[lb] + wb[wave][lb] + rk[k]] = e[k];
        }
    }
    __syncthreads();
    int total = off[FINES_PER_SB];
    for (int i = tid; i < total; i += 256) {
        ull v = staged[i];
        int lb = (int)(v >> 52) & 127;
        pairs2[gbase[lb] + (i - off[lb])] = v;
    }
}

// ---------------- K3: row-partition + per-row wave sort + compact + fence-free last-block scan ----------------
__global__ void __launch_bounds__(256) k_sortrows(const int* __restrict__ fineCursor,
                                                  ull* __restrict__ pairs2,
                                                  int* __restrict__ uniqueCount,
                                                  int* __restrict__ done,
                                                  int* __restrict__ outBase,
                                                  float* __restrict__ out) {
    int b = blockIdx.x;
    int base = b * CAPB;
    int n = fineCursor[b] - base;
    if (n > CAPB) n = CAPB;
    __shared__ ull d[CAPB];
    __shared__ int rcnt[4][16], wb[4][16], roff[17], ucnt[16], ubase[16];
    __shared__ int sFlag;
    __shared__ int partial[256];
    int tid = threadIdx.x, wave = tid >> 6, lane = tid & 63;
    if (tid < 64) ((int*)rcnt)[tid] = 0;
    __syncthreads();
    // single global read: stage entries in regs, rank via per-wave LDS atomics
    ull e[5];
    int rk[5];
#pragma unroll
    for (int k = 0; k < 5; k++) {
        int i = tid + k * 256;
        if (i < n) {
            e[k] = pairs2[base + i];
            rk[k] = atomicAdd(&rcnt[wave][(int)(e[k] >> 48) & 15], 1);
        }
    }
    __syncthreads();
    if (tid < 16) {
        int a0 = rcnt[0][tid], a1 = rcnt[1][tid], a2 = rcnt[2][tid], a3 = rcnt[3][tid];
        wb[0][tid] = 0; wb[1][tid] = a0; wb[2][tid] = a0 + a1; wb[3][tid] = a0 + a1 + a2;
        rcnt[0][tid] = a0 + a1 + a2 + a3;
    }
    __syncthreads();
    if (tid == 0) {
        int acc = 0;
        for (int s = 0; s < 16; s++) { roff[s] = acc; acc += rcnt[0][s]; }
        roff[16] = acc;
    }
    __syncthreads();
#pragma unroll
    for (int k = 0; k < 5; k++) {
        int i = tid + k * 256;
        if (i < n) {
            int rr = (int)(e[k] >> 48) & 15;
            d[roff[rr] + wb[wave][rr] + rk[k]] = e[k];
        }
    }
    __syncthreads();
    // one wave per row: register bitonic + dedupe (4 waves x 4 rows)
    for (int rr = wave; rr < 16; rr += 4) {
        int lo = roff[rr];
        int nr = roff[rr + 1] - lo;
        if (nr > CAPROW) nr = CAPROW;      // safety clamp
        int total;
        if (nr <= 64)       total = sort_row<1>(d + lo, nr, lane);
        else if (nr <= 128) total = sort_row<2>(d + lo, nr, lane);
        else                total = sort_row<4>(d + lo, nr, lane);
        if (lane == 0) ucnt[rr] = total;
    }
    __syncthreads();
    if (tid == 0) {
        int acc = 0;
        for (int s = 0; s < 16; s++) { ubase[s] = acc; acc += ucnt[s]; }
        ucnt[0] += 0;                       // keep ucnt live
        // device-scope publish via returning atomic (LLC-coherent, no L2 writeback)
        int old = atomicExch(&uniqueCount[b], acc);
        // wait only this wave's outstanding vmem (atomic completion == at LLC),
        // then signal. NO __threadfence: that emits buffer_wbl2 (R10: +64us).
        __asm__ volatile("s_waitcnt vmcnt(0)" :: "v"(old) : "memory");
        int prev = atomicAdd(done, 1);
        sFlag = (prev == (int)gridDim.x - 1) ? 1 : 0;
    }
    __syncthreads();
    // copy compacted rows back contiguous per bucket
    for (int rr = wave; rr < 16; rr += 4) {
        int u = ucnt[rr], lo = roff[rr], ub = ubase[rr];
        for (int j = lane; j < u; j += 64)
            pairs2[base + ub + j] = d[lo + j];
    }
    __syncthreads();

    // ---- last-finishing block: exclusive scan over uniqueCount (atomic reads @LLC) ----
    if (sFlag) {
        const int PER = 10;                 // 256*10 = 2560 >= 2500
        int start = tid * PER;
        int v[PER], sum = 0;
#pragma unroll
        for (int k = 0; k < PER; k++) {
            int i = start + k;
            int x = (i < NFINE) ? atomicAdd(&uniqueCount[i], 0) : 0;
            v[k] = sum;
            sum += x;
        }
        partial[tid] = sum;
        __syncthreads();
        for (int off = 1; off < 256; off <<= 1) {
            int add = (tid >= off) ? partial[tid - off] : 0;
            __syncthreads();
            partial[tid] += add;
            __syncthreads();
        }
        int bb = partial[tid] - sum;
#pragma unroll
        for (int k = 0; k < PER; k++) {
            int i = start + k;
            if (i < NFINE) outBase[i] = bb + v[k];
        }
        if (tid == 255) {
            outBase[NFINE] = partial[255];
            out[(size_t)3 * E2] = (float)partial[255];   // num_edges as f32
        }
    }
}

// ---------------- K4: fused pad-fill + write-out, x4 vectorized ----------------
__global__ void __launch_bounds__(256) k_outfill(const int* __restrict__ outBase,
                                                 const ull* __restrict__ pairs2,
                                                 float* __restrict__ out) {
    __shared__ int sOB[NFINE + 1];
    int tid = threadIdx.x;
    for (int i = tid; i <= NFINE; i += 256) sOB[i] = outBase[i];
    __syncthreads();
    int j0 = (blockIdx.x * 256 + tid) * 4;      // grid covers E2 exactly (5000*1024)
    int T = sOB[NFINE];
    float rr[4], cc[4], aa[4];
    int lo = 0;
    if (j0 < T) {
        int hi = NFINE;                          // invariant: sOB[lo] <= j0 < sOB[hi]
        while (hi - lo > 1) {
            int mid = (lo + hi) >> 1;
            if (sOB[mid] <= j0) lo = mid; else hi = mid;
        }
    }
#pragma unroll
    for (int k = 0; k < 4; k++) {
        int j = j0 + k;
        if (j < T) {
            while (lo < NFINE - 1 && sOB[lo + 1] <= j) lo++;   // rare bucket advance
            ull e = pairs2[lo * CAPB + (j - sOB[lo])];
            rr[k] = (float)(int)(e >> 48);
            cc[k] = (float)(int)((e >> 32) & 0xFFFF);
            aa[k] = __uint_as_float((unsigned)(e & 0xFFFFFFFFu));
        } else { rr[k] = -1.0f; cc[k] = -1.0f; aa[k] = 0.0f; }
    }
    *(float4*)(out + j0)          = make_float4(rr[0], rr[1], rr[2], rr[3]);
    *(float4*)(out + E2 + j0)     = make_float4(cc[0], cc[1], cc[2], cc[3]);
    *(float4*)(out + 2 * E2 + j0) = make_float4(aa[0], aa[1], aa[2], aa[3]);
}

extern "C" void kernel_launch(void* const* d_in, const int* in_sizes, int n_in,
                              void* d_out, int out_size, void* d_ws, size_t ws_size,
                              hipStream_t stream) {
    const int*   ei = (const int*)d_in[0];     // [2,E]: rows then cols
    const float* ea = (const float*)d_in[1];   // [E]
    const float* t  = (const float*)d_in[2];   // [1]
    float* out = (float*)d_out;                // 2*E2 indices + E2 attrs + 1 count

    // ws layout: sbCursor[32] (relative) | done[1]+pad to 64 | fineCursor |
    //            uniqueCount | outBase | pairs2 regions  (~25.7 MB total)
    int* sbCursor    = (int*)d_ws;                    // 32 (20 used)
    int* done        = sbCursor + 32;                 // 1
    int* fineCursor  = sbCursor + 64;                 // 2500 (init by k_part1)
    int* uniqueCount = fineCursor + NFINE;            // 2500 (all written before read)
    int* outBase     = uniqueCount + NFINE;           // 2501
    ull* pairs2 = (ull*)(((uintptr_t)(outBase + NFINE + 1) + 15) & ~(uintptr_t)15);  // 2500*CAPB

    // pairs1 lives in d_out (20*SBCAP*8 = 21.6 MB < 61.4 MB): dead before out writes
    ull* pairs1 = (ull*)d_out;

    hipMemsetAsync(sbCursor, 0, 64 * sizeof(int), stream);   // sbCursor + done

    k_part1<<<E_IN / 1024, 256, 0, stream>>>(ei, ea, t, sbCursor, fineCursor, pairs1);
    k_part2<<<NSB * P2_TILES, 256, 0, stream>>>(sbCursor, fineCursor, pairs1, pairs2);
    k_sortrows<<<NFINE, 256, 0, stream>>>(fineCursor, pairs2, uniqueCount, done, outBase, out);
    k_outfill<<<E2 / 1024, 256, 0, stream>>>(outBase, pairs2, out);
}

// Round 12
// 199.241 us; speedup vs baseline: 5.5678x; 1.0622x over previous
//
#include <hip/hip_runtime.h>
#include <stdint.h>

#define NN 40000            // N_NODES
#define E_IN 2560000        // input edges
#define E2 5120000          // 2*E_IN, padded output size
#define NFINE 2500          // fine buckets: r>>4 (16 rows each)
#define NSB 20              // superbuckets: r>>11 (2048 rows each; sb19 partial)
#define SB_SHIFT 11
#define FINES_PER_SB 128
#define P2_TILES 66
#define SBCAP (P2_TILES*2048)  // 135168: mean 131072 + ~11 sigma (sigma~360)
#define CAPB 1280           // fine region: mean 1024 + 8 sigma (sigma~32)
#define CAPROW 256          // per-row safety clamp

typedef unsigned long long ull;

// ---------------- wave-level u32-key bitonic + dedupe for one row ----------------
// Entries in a row share r; sort key = (c<<8)|slot (u32, 1 shfl/stage), gather
// full u64 entries by slot afterward. Compacted result at dRow[0..total).
template<int L>
__device__ __forceinline__ int sort_row(ull* dRow, int nr, int lane) {
    const int m = 64 * L;
    unsigned key[L];
#pragma unroll
    for (int s = 0; s < L; s++) {
        int v = s * 64 + lane;
        key[s] = (v < nr) ? ((((unsigned)(dRow[v] >> 32) & 0xFFFFu) << 8) | (unsigned)v)
                          : 0xFFFFFFFFu;
    }
    for (int k = 2; k <= m; k <<= 1) {
        for (int j = k >> 1; j > 0; j >>= 1) {
            if (j >= 64) {
                int js = j >> 6;
#pragma unroll
                for (int s = 0; s < L; s++) {
                    int s2 = s ^ js;
                    if (s2 > s) {
                        bool up = (((s * 64) & k) == 0);   // k>=128: lane bits irrelevant
                        unsigned a = key[s], b = key[s2];
                        bool sw = up ? (a > b) : (a < b);
                        key[s]  = sw ? b : a;
                        key[s2] = sw ? a : b;
                    }
                }
            } else {
#pragma unroll
                for (int s = 0; s < L; s++) {
                    unsigned partner = __shfl_xor(key[s], j, 64);
                    int v = s * 64 + lane;
                    bool up = ((v & k) == 0);
                    bool lower = ((lane & j) == 0);
                    bool keepmin = (lower == up);
                    unsigned mn = key[s] < partner ? key[s] : partner;
                    unsigned mx = key[s] < partner ? partner : key[s];
                    key[s] = keepmin ? mn : mx;
                }
            }
        }
    }
    ull lmask = (1ull << lane) - 1;
    bool head[L];
    int rank[L];
    int base = 0;
#pragma unroll
    for (int s = 0; s < L; s++) {
        unsigned pv = __shfl_up(key[s], 1, 64);
        unsigned tl = (s > 0) ? __shfl(key[s - 1], 63, 64) : 0u;
        unsigned prev = (lane == 0) ? tl : pv;
        int v = s * 64 + lane;
        head[s] = (key[s] != 0xFFFFFFFFu) && (v == 0 || (key[s] >> 8) != (prev >> 8));
        ull msk = __ballot(head[s]);
        rank[s] = base + __popcll(msk & lmask);
        base += __popcll(msk);
    }
    int total = base;
    ull full[L];
#pragma unroll
    for (int s = 0; s < L; s++)
        full[s] = (key[s] != 0xFFFFFFFFu) ? dRow[key[s] & 255u] : 0ull;
    __builtin_amdgcn_wave_barrier();     // gathers before overwrite (DS in-order per wave)
#pragma unroll
    for (int s = 0; s < L; s++) {
        int v = s * 64 + lane;
        if (v < nr) dRow[v] = full[s];
    }
    __builtin_amdgcn_wave_barrier();
    float acc[L];
#pragma unroll
    for (int s = 0; s < L; s++) {
        if (head[s]) {
            float a = __uint_as_float((unsigned)(full[s] & 0xFFFFFFFFu));
            int v = s * 64 + lane;
            for (int q = v + 1; q < nr; q++) {
                ull x = dRow[q];
                if ((x >> 32) != (full[s] >> 32)) break;
                a += __uint_as_float((unsigned)(x & 0xFFFFFFFFu));
            }
            acc[s] = a;
        }
    }
    __builtin_amdgcn_wave_barrier();     // run reads before compacted writes
#pragma unroll
    for (int s = 0; s < L; s++) {
        if (head[s])
            dRow[rank[s]] = (full[s] & 0xFFFFFFFF00000000ull) | (ull)__float_as_uint(acc[s]);
    }
    return total;
}

// ---------------- K1: partition pass 1 (vectorized loads, per-wave counters) ----------------
// sbCursor is RELATIVE (memset 0 host-side); region base added here. grid==2500
// ==NFINE: each block also inits one fineCursor slot (read only after boundary).
__global__ void __launch_bounds__(256) k_part1(const int* __restrict__ ei,
                                               const float* __restrict__ ea,
                                               const float* __restrict__ t,
                                               int* __restrict__ sbCursor,
                                               int* __restrict__ fineCursor,
                                               ull* __restrict__ pairs1) {
    if (threadIdx.x == 0) fineCursor[blockIdx.x] = blockIdx.x * CAPB;

    __shared__ ull staged[2048];
    __shared__ int cnt[4][NSB], wb[4][NSB], off[NSB + 1], gbase[NSB];
    int tid = threadIdx.x, wave = tid >> 6;
    if (tid < 4 * NSB) ((int*)cnt)[tid] = 0;
    __syncthreads();
    float t0 = t[0];
    int i0 = blockIdx.x * 1024 + tid * 4;       // 4 consecutive edges per thread

    int4   r4 = *(const int4*)(ei + i0);
    int4   c4 = *(const int4*)(ei + E_IN + i0);
    float4 a4 = *(const float4*)(ea + i0);
    int   rr[4] = { r4.x, r4.y, r4.z, r4.w };
    int   cc[4] = { c4.x, c4.y, c4.z, c4.w };
    float aa[4] = { a4.x, a4.y, a4.z, a4.w };

    ull eA[4], eB[4];
    int rkA[4], rkB[4];
    bool keep[4];
#pragma unroll
    for (int k = 0; k < 4; k++) {
        keep[k] = (aa[k] <= t0);
        if (keep[k]) {
            unsigned ab = __float_as_uint(aa[k]);
            eA[k] = ((ull)(unsigned)rr[k] << 48) | ((ull)(unsigned)cc[k] << 32) | ab;
            eB[k] = ((ull)(unsigned)cc[k] << 48) | ((ull)(unsigned)rr[k] << 32) | ab;
            rkA[k] = atomicAdd(&cnt[wave][rr[k] >> SB_SHIFT], 1);
            rkB[k] = atomicAdd(&cnt[wave][cc[k] >> SB_SHIFT], 1);
        }
    }
    __syncthreads();
    if (tid < NSB) {
        int a0 = cnt[0][tid], a1 = cnt[1][tid], a2 = cnt[2][tid], a3 = cnt[3][tid];
        wb[0][tid] = 0; wb[1][tid] = a0; wb[2][tid] = a0 + a1; wb[3][tid] = a0 + a1 + a2;
        cnt[0][tid] = a0 + a1 + a2 + a3;        // bucket total
    }
    __syncthreads();
    if (tid == 0) {
        int acc = 0;
        for (int s = 0; s < NSB; s++) { off[s] = acc; acc += cnt[0][s]; }
        off[NSB] = acc;
    }
    __syncthreads();
    if (tid < NSB) gbase[tid] = tid * SBCAP + atomicAdd(&sbCursor[tid], cnt[0][tid]);
#pragma unroll
    for (int k = 0; k < 4; k++) {
        if (keep[k]) {
            int sA = rr[k] >> SB_SHIFT, sB = cc[k] >> SB_SHIFT;
            staged[off[sA] + wb[wave][sA] + rkA[k]] = eA[k];
            staged[off[sB] + wb[wave][sB] + rkB[k]] = eB[k];
        }
    }
    __syncthreads();
    int total = off[NSB];
    for (int i = tid; i < total; i += 256) {
        ull e = staged[i];
        int sb = (int)(e >> 59);
        pairs1[gbase[sb] + (i - off[sb])] = e;
    }
}

// ---------------- K2: partition pass 2 (per-wave counters, contiguous 64B loads) ----------------
__global__ void __launch_bounds__(256) k_part2(const int* __restrict__ sbCursor,
                                               int* __restrict__ fineCursor,
                                               const ull* __restrict__ pairs1,
                                               ull* __restrict__ pairs2) {
    int sb = blockIdx.x / P2_TILES;
    int tile = blockIdx.x % P2_TILES;
    int len = sbCursor[sb];                     // relative cursor == count
    if (len > SBCAP) len = SBCAP;               // defensive clamp
    int start = tile * 2048;
    if (start >= len) return;
    int cntT = len - start; if (cntT > 2048) cntT = 2048;
    const ull* src = pairs1 + sb * SBCAP + start;

    int fineFirst = sb * FINES_PER_SB;
    int nF = NFINE - fineFirst; if (nF > FINES_PER_SB) nF = FINES_PER_SB;

    __shared__ ull staged[2048];
    __shared__ int cnt[4][FINES_PER_SB], wb[4][FINES_PER_SB];
    __shared__ int off[FINES_PER_SB + 1], gbase[FINES_PER_SB];
    int tid = threadIdx.x, wave = tid >> 6;
    for (int i = tid; i < 4 * FINES_PER_SB; i += 256) ((int*)cnt)[i] = 0;
    if (tid < FINES_PER_SB) gbase[tid] = 0;     // defense
    __syncthreads();

    ull e[8];
    int rk[8];
    int tb = tid * 8;                           // 8 contiguous entries -> 64B/thread
#pragma unroll
    for (int k = 0; k < 8; k++) {
        int i = tb + k;
        if (i < cntT) {
            e[k] = src[i];
            rk[k] = atomicAdd(&cnt[wave][(int)(e[k] >> 52) & 127], 1);
        }
    }
    __syncthreads();
    if (tid < FINES_PER_SB) {
        int a0 = cnt[0][tid], a1 = cnt[1][tid], a2 = cnt[2][tid], a3 = cnt[3][tid];
        wb[0][tid] = 0; wb[1][tid] = a0; wb[2][tid] = a0 + a1; wb[3][tid] = a0 + a1 + a2;
        cnt[0][tid] = a0 + a1 + a2 + a3;
    }
    __syncthreads();
    if (tid == 0) {
        int acc = 0;
        for (int s = 0; s < FINES_PER_SB; s++) { off[s] = acc; acc += cnt[0][s]; }
        off[FINES_PER_SB] = acc;
    }
    __syncthreads();
    if (tid < nF) gbase[tid] = atomicAdd(&fineCursor[fineFirst + tid], cnt[0][tid]);
#pragma unroll
    for (int k = 0; k < 8; k++) {
        int i = tb + k;
        if (i < cntT) {
            int lb = (int)(e[k] >> 52) & 127;
            staged[off[lb] + wb[wave][lb] + rk[k]] = e[k];
        }
    }
    __syncthreads();
    int total = off[FINES_PER_SB];
    for (int i = tid; i < total; i += 256) {
        ull v = staged[i];
        int lb = (int)(v >> 52) & 127;
        pairs2[gbase[lb] + (i - off[lb])] = v;
    }
}

// ---------------- K3: row-partition + per-row wave sort + compact (R7-proven body) ----------------
__global__ void __launch_bounds__(256) k_sortrows(const int* __restrict__ fineCursor,
                                                  ull* __restrict__ pairs2,
                                                  int* __restrict__ uniqueCount) {
    int b = blockIdx.x;
    int base = b * CAPB;
    int n = fineCursor[b] - base;
    if (n > CAPB) n = CAPB;
    __shared__ ull d[CAPB];
    __shared__ int rcnt[16], roff[17], ucnt[16], ubase[16];
    int tid = threadIdx.x;
    if (tid < 16) rcnt[tid] = 0;
    __syncthreads();
    // single global read: stage entries in regs, rank via LDS atomics
    ull e[5];
    int rk[5];
#pragma unroll
    for (int k = 0; k < 5; k++) {
        int i = tid + k * 256;
        if (i < n) {
            e[k] = pairs2[base + i];
            rk[k] = atomicAdd(&rcnt[(int)(e[k] >> 48) & 15], 1);
        }
    }
    __syncthreads();
    if (tid == 0) {
        int acc = 0;
        for (int s = 0; s < 16; s++) { roff[s] = acc; acc += rcnt[s]; }
        roff[16] = acc;
    }
    __syncthreads();
#pragma unroll
    for (int k = 0; k < 5; k++) {
        int i = tid + k * 256;
        if (i < n) d[roff[(int)(e[k] >> 48) & 15] + rk[k]] = e[k];
    }
    __syncthreads();
    // one wave per row: register bitonic + dedupe (4 waves x 4 rows)
    int lane = tid & 63, wave = tid >> 6;
    for (int rr = wave; rr < 16; rr += 4) {
        int lo = roff[rr];
        int nr = roff[rr + 1] - lo;
        if (nr > CAPROW) nr = CAPROW;      // safety clamp
        int total;
        if (nr <= 64)       total = sort_row<1>(d + lo, nr, lane);
        else if (nr <= 128) total = sort_row<2>(d + lo, nr, lane);
        else                total = sort_row<4>(d + lo, nr, lane);
        if (lane == 0) ucnt[rr] = total;
    }
    __syncthreads();
    if (tid == 0) {
        int acc = 0;
        for (int s = 0; s < 16; s++) { ubase[s] = acc; acc += ucnt[s]; }
        uniqueCount[b] = acc;
    }
    __syncthreads();
    // copy compacted rows back contiguous per bucket
    for (int rr = wave; rr < 16; rr += 4) {
        int u = ucnt[rr], lo = roff[rr], ub = ubase[rr];
        for (int j = lane; j < u; j += 64)
            pairs2[base + ub + j] = d[lo + j];
    }
}

// ---------------- K4: single-block exclusive scan over n<=3072 (R7-proven) ----------------
__global__ void __launch_bounds__(1024) k_scan(const int* __restrict__ in, int n,
                                               int* __restrict__ outExcl,
                                               float* __restrict__ totalDst) {
    __shared__ int partial[1024];
    int tid = threadIdx.x;
    int start = tid * 3;
    int v[3], sum = 0;
#pragma unroll
    for (int k = 0; k < 3; k++) {
        int i = start + k;
        int x = (i < n) ? in[i] : 0;
        v[k] = sum;                 // local exclusive prefix
        sum += x;
    }
    partial[tid] = sum;
    __syncthreads();
    for (int off = 1; off < 1024; off <<= 1) {
        int add = (tid >= off) ? partial[tid - off] : 0;
        __syncthreads();
        partial[tid] += add;
        __syncthreads();
    }
    int base = partial[tid] - sum;
#pragma unroll
    for (int k = 0; k < 3; k++) {
        int i = start + k;
        if (i < n) outExcl[i] = base + v[k];
    }
    if (tid == 1023) {
        outExcl[n] = partial[1023];
        if (totalDst) totalDst[0] = (float)partial[1023];
    }
}

// ---------------- K5: fused pad-fill + write-out, x4 vectorized ----------------
__global__ void __launch_bounds__(256) k_outfill(const int* __restrict__ outBase,
                                                 const ull* __restrict__ pairs2,
                                                 float* __restrict__ out) {
    __shared__ int sOB[NFINE + 1];
    int tid = threadIdx.x;
    for (int i = tid; i <= NFINE; i += 256) sOB[i] = outBase[i];
    __syncthreads();
    int j0 = (blockIdx.x * 256 + tid) * 4;      // grid covers E2 exactly (5000*1024)
    int T = sOB[NFINE];
    float rr[4], cc[4], aa[4];
    int lo = 0;
    if (j0 < T) {
        int hi = NFINE;                          // invariant: sOB[lo] <= j0 < sOB[hi]
        while (hi - lo > 1) {
            int mid = (lo + hi) >> 1;
            if (sOB[mid] <= j0) lo = mid; else hi = mid;
        }
    }
#pragma unroll
    for (int k = 0; k < 4; k++) {
        int j = j0 + k;
        if (j < T) {
            while (lo < NFINE - 1 && sOB[lo + 1] <= j) lo++;   // rare bucket advance
            ull e = pairs2[lo * CAPB + (j - sOB[lo])];
            rr[k] = (float)(int)(e >> 48);
            cc[k] = (float)(int)((e >> 32) & 0xFFFF);
            aa[k] = __uint_as_float((unsigned)(e & 0xFFFFFFFFu));
        } else { rr[k] = -1.0f; cc[k] = -1.0f; aa[k] = 0.0f; }
    }
    *(float4*)(out + j0)          = make_float4(rr[0], rr[1], rr[2], rr[3]);
    *(float4*)(out + E2 + j0)     = make_float4(cc[0], cc[1], cc[2], cc[3]);
    *(float4*)(out + 2 * E2 + j0) = make_float4(aa[0], aa[1], aa[2], aa[3]);
}

extern "C" void kernel_launch(void* const* d_in, const int* in_sizes, int n_in,
                              void* d_out, int out_size, void* d_ws, size_t ws_size,
                              hipStream_t stream) {
    const int*   ei = (const int*)d_in[0];     // [2,E]: rows then cols
    const float* ea = (const float*)d_in[1];   // [E]
    const float* t  = (const float*)d_in[2];   // [1]
    float* out = (float*)d_out;                // 2*E2 indices + E2 attrs + 1 count

    // ws layout: sbCursor[32] (relative) | pad to 64 | fineCursor | uniqueCount |
    //            outBase | pairs2 regions  (~25.7 MB total)
    int* sbCursor    = (int*)d_ws;                    // 32 (20 used)
    int* fineCursor  = sbCursor + 64;                 // 2500 (init by k_part1)
    int* uniqueCount = fineCursor + NFINE;            // 2500
    int* outBase     = uniqueCount + NFINE;           // 2501
    ull* pairs2 = (ull*)(((uintptr_t)(outBase + NFINE + 1) + 15) & ~(uintptr_t)15);  // 2500*CAPB

    // pairs1 lives in d_out (20*SBCAP*8 = 21.6 MB < 61.4 MB): dead before out writes
    ull* pairs1 = (ull*)d_out;

    hipMemsetAsync(sbCursor, 0, 64 * sizeof(int), stream);   // relative sbCursor

    k_part1<<<E_IN / 1024, 256, 0, stream>>>(ei, ea, t, sbCursor, fineCursor, pairs1);
    k_part2<<<NSB * P2_TILES, 256, 0, stream>>>(sbCursor, fineCursor, pairs1, pairs2);
    k_sortrows<<<NFINE, 256, 0, stream>>>(fineCursor, pairs2, uniqueCount);
    k_scan<<<1, 1024, 0, stream>>>(uniqueCount, NFINE, outBase, out + (size_t)3 * E2);
    k_outfill<<<E2 / 1024, 256, 0, stream>>>(outBase, pairs2, out);
}